// Round 5
// baseline (1322.133 us; speedup 1.0000x reference)
//
#include <hip/hip_runtime.h>
#include <math.h>

#define NB_ROWS 8192
#define DDIM 1024
#define PSZ ((size_t)NB_ROWS * DDIM)

typedef _Float16 f16x8 __attribute__((ext_vector_type(8)));
typedef _Float16 f16x4 __attribute__((ext_vector_type(4)));
typedef float f32x4 __attribute__((ext_vector_type(4)));

#define LO_SCALE 1024.0f
#define LO_INV (1.0f / 1024.0f)

__device__ __forceinline__ void gload_lds16(const void* g, void* l) {
  __builtin_amdgcn_global_load_lds((const __attribute__((address_space(1))) void*)g,
                                   (__attribute__((address_space(3))) void*)l, 16, 0, 0);
}

__device__ __forceinline__ bool pair_better(float s, int j, float v, int i) {
  return (s > v) || (s == v && j < i);
}

__device__ __forceinline__ void upd4(float s, int jj,
                                     float& v0, int& i0, float& v1, int& i1,
                                     float& v2, int& i2, float& v3, int& i3) {
  if (pair_better(s, jj, v0, i0)) { v3 = v2; i3 = i2; v2 = v1; i2 = i1; v1 = v0; i1 = i0; v0 = s; i0 = jj; }
  else if (pair_better(s, jj, v1, i1)) { v3 = v2; i3 = i2; v2 = v1; i2 = i1; v1 = s; i1 = jj; }
  else if (pair_better(s, jj, v2, i2)) { v3 = v2; i3 = i2; v2 = s; i2 = jj; }
  else if (pair_better(s, jj, v3, i3)) { v3 = s; i3 = jj; }
}

__device__ __forceinline__ void upd3(float s, int jj, float& v0, int& i0,
                                     float& v1, int& i1, float& v2, int& i2) {
  if (pair_better(s, jj, v0, i0)) { v2 = v1; i2 = i1; v1 = v0; i1 = i0; v0 = s; i0 = jj; }
  else if (pair_better(s, jj, v1, i1)) { v2 = v1; i2 = i1; v1 = s; i1 = jj; }
  else if (pair_better(s, jj, v2, i2)) { v2 = s; i2 = jj; }
}

// ---------------- scan: bank2batch + query list per modality ----------------
__global__ void scan_kernel(const int* __restrict__ miss, int* __restrict__ meta,
                            int* __restrict__ b2b, int* __restrict__ qrw) {
  const int m = blockIdx.x, t = threadIdx.x, tmod = m + 1;
  __shared__ int cnt[256];
  const int base = t * 32;
  int c = 0;
  for (int i = 0; i < 32; ++i) c += (miss[base + i] != tmod) ? 1 : 0;
  cnt[t] = c; __syncthreads();
  for (int s = 1; s < 256; s <<= 1) {
    int v = (t >= s) ? cnt[t - s] : 0;
    __syncthreads();
    cnt[t] += v;
    __syncthreads();
  }
  const int Nb = cnt[255];
  int pos = cnt[t] - c;
  for (int i = 0; i < 32; ++i) {
    int r = base + i;
    if (miss[r] != tmod) b2b[m * NB_ROWS + (pos++)] = r;
  }
  __syncthreads();
  int q = 0;
  for (int i = 0; i < 32; ++i) {
    int r = base + i;
    q += (miss[r] == tmod && r < Nb) ? 1 : 0;
  }
  cnt[t] = q; __syncthreads();
  for (int s = 1; s < 256; s <<= 1) {
    int v = (t >= s) ? cnt[t - s] : 0;
    __syncthreads();
    cnt[t] += v;
    __syncthreads();
  }
  int nQ = cnt[255];
  if (nQ > 4096) nQ = 4096;
  int qpos = cnt[t] - q;
  for (int i = 0; i < 32; ++i) {
    int r = base + i;
    if (miss[r] == tmod && r < Nb && qpos < 4096) qrw[m * 4096 + (qpos++)] = r;
  }
  for (int i = nQ + t; i < 4096; i += 256) qrw[m * 4096 + i] = 0;  // pad tail
  if (t == 0) { meta[2 * m] = Nb; meta[2 * m + 1] = nQ; }
}

// ------------- transpose + fp16 split: W[K][N] -> Th/Tl[N][K] ---------------
__global__ void tsplit(const float* __restrict__ W, _Float16* __restrict__ Th,
                       _Float16* __restrict__ Tl, int K, int N) {
  __shared__ float tile[32][33];
  const int k0 = blockIdx.x * 32, n0 = blockIdx.y * 32;
  const int tx = threadIdx.x, ty = threadIdx.y;
  for (int i = ty; i < 32; i += 8)
    tile[i][tx] = W[(size_t)(k0 + i) * N + n0 + tx];
  __syncthreads();
  for (int i = ty; i < 32; i += 8) {
    float v = tile[tx][i];
    _Float16 h = (_Float16)v;
    Th[(size_t)(n0 + i) * K + k0 + tx] = h;
    if (Tl) Tl[(size_t)(n0 + i) * K + k0 + tx] = (_Float16)((v - (float)h) * LO_SCALE);
  }
}

__device__ __forceinline__ f16x8 cvt_hi8(float4 a, float4 b) {
  f16x8 r;
  r[0] = (_Float16)a.x; r[1] = (_Float16)a.y; r[2] = (_Float16)a.z; r[3] = (_Float16)a.w;
  r[4] = (_Float16)b.x; r[5] = (_Float16)b.y; r[6] = (_Float16)b.z; r[7] = (_Float16)b.w;
  return r;
}
__device__ __forceinline__ f16x8 cvt_lo8(float4 a, float4 b, f16x8 h) {
  f16x8 r;
  r[0] = (_Float16)((a.x - (float)h[0]) * LO_SCALE);
  r[1] = (_Float16)((a.y - (float)h[1]) * LO_SCALE);
  r[2] = (_Float16)((a.z - (float)h[2]) * LO_SCALE);
  r[3] = (_Float16)((a.w - (float)h[3]) * LO_SCALE);
  r[4] = (_Float16)((b.x - (float)h[4]) * LO_SCALE);
  r[5] = (_Float16)((b.y - (float)h[5]) * LO_SCALE);
  r[6] = (_Float16)((b.z - (float)h[6]) * LO_SCALE);
  r[7] = (_Float16)((b.w - (float)h[7]) * LO_SCALE);
  return r;
}

// ------------- row-major fp16 split: X fp32 -> Ah/Al (same layout) ----------
__global__ void xsplit(const float* __restrict__ X, _Float16* __restrict__ Ah,
                       _Float16* __restrict__ Al) {
  const size_t idx = ((size_t)blockIdx.x * 256 + threadIdx.x) * 8;
  float4 f0 = *(const float4*)(X + idx);
  float4 f1 = *(const float4*)(X + idx + 4);
  f16x8 hi = cvt_hi8(f0, f1);
  f16x8 lo = cvt_lo8(f0, f1, hi);
  *(f16x8*)(Ah + idx) = hi;
  *(f16x8*)(Al + idx) = lo;
}

// ---- MFMA split GEMM: proj = A(hi/lo)[8192,2048] @ Bt(hi/lo)[1024,2048]^T + bias
__launch_bounds__(256, 2)
__global__ void gemm_proj_mfma(const _Float16* __restrict__ Ah, const _Float16* __restrict__ Al,
                               const _Float16* __restrict__ Bh, const _Float16* __restrict__ Bl,
                               const float* __restrict__ bias,
                               _Float16* __restrict__ Ph, _Float16* __restrict__ Pl) {
  const int K = 2048;
  __shared__ __align__(16) _Float16 Abuf[128 * 64];
  __shared__ __align__(16) _Float16 Bbuf[128 * 64];
  const int t = threadIdx.x;
  const int w = t >> 6, ln = t & 63;
  const int n0 = blockIdx.x * 128, m0 = blockIdx.y * 128;
  const int moff = (w & 1) * 64, noff = (w >> 1) * 64;
  const int lq = ln >> 4, lr = ln & 15;

  const _Float16* as[4]; const _Float16* bs[4];
  _Float16* ad[4]; _Float16* bd[4];
#pragma unroll
  for (int p = 0; p < 4; ++p) {
    int r = p * 32 + w * 8 + (ln >> 3);
    int l = (ln & 7) ^ (r & 7);
    as[p] = (l < 4) ? (Ah + (size_t)(m0 + r) * K + l * 8)
                    : (Al + (size_t)(m0 + r) * K + (l - 4) * 8);
    bs[p] = (l < 4) ? (Bh + (size_t)(n0 + r) * K + l * 8)
                    : (Bl + (size_t)(n0 + r) * K + (l - 4) * 8);
    ad[p] = &Abuf[(p * 32 + w * 8) * 64];
    bd[p] = &Bbuf[(p * 32 + w * 8) * 64];
  }

  f32x4 acc[4][4] = {};
  f32x4 acc2[4][4] = {};

  for (int k0 = 0; k0 < K; k0 += 32) {
#pragma unroll
    for (int p = 0; p < 4; ++p) {
      gload_lds16(as[p] + k0, ad[p]);
      gload_lds16(bs[p] + k0, bd[p]);
    }
    __syncthreads();
    f16x8 ahi[4], alo[4];
#pragma unroll
    for (int mt = 0; mt < 4; ++mt) {
      int r = moff + mt * 16 + lr;
      ahi[mt] = *(f16x8*)&Abuf[r * 64 + ((lq) ^ (r & 7)) * 8];
      alo[mt] = *(f16x8*)&Abuf[r * 64 + ((lq + 4) ^ (r & 7)) * 8];
    }
#pragma unroll
    for (int nt = 0; nt < 4; ++nt) {
      int r = noff + nt * 16 + lr;
      f16x8 bhi = *(f16x8*)&Bbuf[r * 64 + ((lq) ^ (r & 7)) * 8];
      f16x8 blo = *(f16x8*)&Bbuf[r * 64 + ((lq + 4) ^ (r & 7)) * 8];
#pragma unroll
      for (int mt = 0; mt < 4; ++mt) {
        acc[mt][nt]  = __builtin_amdgcn_mfma_f32_16x16x32_f16(ahi[mt], bhi, acc[mt][nt], 0, 0, 0);
        acc2[mt][nt] = __builtin_amdgcn_mfma_f32_16x16x32_f16(ahi[mt], blo, acc2[mt][nt], 0, 0, 0);
        acc2[mt][nt] = __builtin_amdgcn_mfma_f32_16x16x32_f16(alo[mt], bhi, acc2[mt][nt], 0, 0, 0);
      }
    }
    __syncthreads();
  }
#pragma unroll
  for (int nt = 0; nt < 4; ++nt) {
    int col = n0 + noff + nt * 16 + lr;
    float bv = bias[col];
#pragma unroll
    for (int mt = 0; mt < 4; ++mt) {
      int row = m0 + moff + mt * 16 + lq * 4;
#pragma unroll
      for (int r = 0; r < 4; ++r) {
        float v = acc[mt][nt][r] + acc2[mt][nt][r] * LO_INV + bv;
        _Float16 h = (_Float16)v;
        Ph[(size_t)(row + r) * DDIM + col] = h;
        Pl[(size_t)(row + r) * DDIM + col] = (_Float16)((v - (float)h) * LO_SCALE);
      }
    }
  }
}

// ---- MFMA 1-pass approx sim (hi-only, BK=64): S = bank_hi[qrw] . bank_hi ----
// Selection-grade only (err ~1e-5); exact rescore happens in topk_fill.
__launch_bounds__(256, 2)
__global__ void gemm_sim_mfma(const _Float16* __restrict__ bh,
                              const int* __restrict__ qrw_m, const int* __restrict__ meta,
                              const int* __restrict__ miss, int mmod, int qoff,
                              float* __restrict__ S) {
  const int Nb = meta[2 * mmod], nQ = meta[2 * mmod + 1];
  const int n0 = blockIdx.x * 128, m0 = blockIdx.y * 128;
  if (qoff + m0 >= nQ || n0 >= Nb) return;
  __shared__ __align__(16) _Float16 Abuf[128 * 64];
  __shared__ __align__(16) _Float16 Bbuf[128 * 64];
  const int t = threadIdx.x;
  const int w = t >> 6, ln = t & 63;
  const int moff = (w & 1) * 64, noff = (w >> 1) * 64;
  const int lq = ln >> 4, lr = ln & 15;

  const _Float16* as[4]; const _Float16* bs[4];
  _Float16* ad[4]; _Float16* bd[4];
#pragma unroll
  for (int p = 0; p < 4; ++p) {
    int r = p * 32 + w * 8 + (ln >> 3);
    int l = (ln & 7) ^ (r & 7);
    int q = qoff + m0 + r; if (q > 4095) q = 4095;
    int arow = qrw_m[q];
    as[p] = bh + (size_t)arow * DDIM + l * 8;
    bs[p] = bh + (size_t)(n0 + r) * DDIM + l * 8;
    ad[p] = &Abuf[(p * 32 + w * 8) * 64];
    bd[p] = &Bbuf[(p * 32 + w * 8) * 64];
  }

  f32x4 acc[4][4] = {};

  for (int k0 = 0; k0 < DDIM; k0 += 64) {
#pragma unroll
    for (int p = 0; p < 4; ++p) {
      gload_lds16(as[p] + k0, ad[p]);
      gload_lds16(bs[p] + k0, bd[p]);
    }
    __syncthreads();
#pragma unroll
    for (int ks = 0; ks < 2; ++ks) {
      f16x8 a[4];
#pragma unroll
      for (int mt = 0; mt < 4; ++mt) {
        int r = moff + mt * 16 + lr;
        a[mt] = *(f16x8*)&Abuf[r * 64 + ((ks * 4 + lq) ^ (r & 7)) * 8];
      }
#pragma unroll
      for (int nt = 0; nt < 4; ++nt) {
        int r = noff + nt * 16 + lr;
        f16x8 b = *(f16x8*)&Bbuf[r * 64 + ((ks * 4 + lq) ^ (r & 7)) * 8];
#pragma unroll
        for (int mt = 0; mt < 4; ++mt)
          acc[mt][nt] = __builtin_amdgcn_mfma_f32_16x16x32_f16(a[mt], b, acc[mt][nt], 0, 0, 0);
      }
    }
    __syncthreads();
  }
#pragma unroll
  for (int nt = 0; nt < 4; ++nt) {
    int col = n0 + noff + nt * 16 + lr;
    const bool colok = (col < Nb) && (miss[col] != mmod + 1);  // col_valid, batch-indexed (source bug kept)
#pragma unroll
    for (int mt = 0; mt < 4; ++mt) {
      int lrow = m0 + moff + mt * 16 + lq * 4;
#pragma unroll
      for (int r = 0; r < 4; ++r) {
        if (qoff + lrow + r < nQ)
          S[(size_t)(lrow + r) * NB_ROWS + col] = colok ? acc[mt][nt][r] : -INFINITY;
      }
    }
  }
}

// ---- MFMA fp16 GEMM: H = relu(concat(P hi-planes) @ W1 + b1), fp16 out -----
__launch_bounds__(256, 2)
__global__ void gemm_h1_mfma(const _Float16* __restrict__ P, const _Float16* __restrict__ W1t,
                             const float* __restrict__ bias, _Float16* __restrict__ H) {
  const int K = 3072;
  __shared__ __align__(16) _Float16 Abuf[128 * 64];
  __shared__ __align__(16) _Float16 Bbuf[128 * 64];
  const int t = threadIdx.x;
  const int w = t >> 6, ln = t & 63;
  const int n0 = blockIdx.x * 128, m0 = blockIdx.y * 128;
  const int moff = (w & 1) * 64, noff = (w >> 1) * 64;
  const int lq = ln >> 4, lr = ln & 15;

  size_t aoff[4]; const _Float16* bs[4];
  _Float16* ad[4]; _Float16* bd[4];
#pragma unroll
  for (int p = 0; p < 4; ++p) {
    int r = p * 32 + w * 8 + (ln >> 3);
    int l = (ln & 7) ^ (r & 7);
    aoff[p] = ((size_t)(m0 + r) << 10) + (size_t)(l * 8);
    bs[p] = W1t + (size_t)(n0 + r) * K + l * 8;
    ad[p] = &Abuf[(p * 32 + w * 8) * 64];
    bd[p] = &Bbuf[(p * 32 + w * 8) * 64];
  }

  f32x4 acc[4][4] = {};

  for (int k0 = 0; k0 < K; k0 += 64) {
    const _Float16* aplane = P + ((size_t)(k0 >> 10) * 2) * PSZ + (k0 & 1023);
#pragma unroll
    for (int p = 0; p < 4; ++p) {
      gload_lds16(aplane + aoff[p], ad[p]);
      gload_lds16(bs[p] + k0, bd[p]);
    }
    __syncthreads();
#pragma unroll
    for (int ks = 0; ks < 2; ++ks) {
      f16x8 a[4];
#pragma unroll
      for (int mt = 0; mt < 4; ++mt) {
        int r = moff + mt * 16 + lr;
        a[mt] = *(f16x8*)&Abuf[r * 64 + ((ks * 4 + lq) ^ (r & 7)) * 8];
      }
#pragma unroll
      for (int nt = 0; nt < 4; ++nt) {
        int r = noff + nt * 16 + lr;
        f16x8 b = *(f16x8*)&Bbuf[r * 64 + ((ks * 4 + lq) ^ (r & 7)) * 8];
#pragma unroll
        for (int mt = 0; mt < 4; ++mt)
          acc[mt][nt] = __builtin_amdgcn_mfma_f32_16x16x32_f16(a[mt], b, acc[mt][nt], 0, 0, 0);
      }
    }
    __syncthreads();
  }
#pragma unroll
  for (int nt = 0; nt < 4; ++nt) {
    int col = n0 + noff + nt * 16 + lr;
    float bv = bias[col];
#pragma unroll
    for (int mt = 0; mt < 4; ++mt) {
      int row = m0 + moff + mt * 16 + lq * 4;
#pragma unroll
      for (int r = 0; r < 4; ++r)
        H[(size_t)(row + r) * DDIM + col] = (_Float16)fmaxf(acc[mt][nt][r] + bv, 0.f);
    }
  }
}

// ---------------- bank build (fused norm), topk+rescore+fill ----------------
__global__ void build_bnk(const _Float16* __restrict__ Phm, const _Float16* __restrict__ Plm,
                          const int* __restrict__ b2bm, const int* __restrict__ meta,
                          int mmod, _Float16* __restrict__ bnh, _Float16* __restrict__ bnl) {
  const int j = blockIdx.x, t = threadIdx.x;
  const int Nb = meta[2 * mmod];
  const size_t o = (size_t)j * DDIM + t * 4;
  if (j >= Nb) {
    *(f16x4*)&bnh[o] = (f16x4)0;
    *(f16x4*)&bnl[o] = (f16x4)0;
    return;
  }
  const int b = b2bm[j];
  f16x4 h = *(const f16x4*)&Phm[(size_t)b * DDIM + t * 4];
  f16x4 l = *(const f16x4*)&Plm[(size_t)b * DDIM + t * 4];
  float v[4]; float s = 0.f;
#pragma unroll
  for (int i = 0; i < 4; ++i) {
    v[i] = (float)h[i] + (float)l[i] * LO_INV;
    s += v[i] * v[i];
  }
  for (int ofs = 32; ofs > 0; ofs >>= 1) s += __shfl_down(s, ofs, 64);
  __shared__ float ls[4];
  if ((t & 63) == 0) ls[t >> 6] = s;
  __syncthreads();
  const float inv = 1.0f / fmaxf(sqrtf(ls[0] + ls[1] + ls[2] + ls[3]), 1e-8f);
  f16x4 hv, lv;
#pragma unroll
  for (int i = 0; i < 4; ++i) {
    float x = v[i] * inv;
    hv[i] = (_Float16)x;
    lv[i] = (_Float16)((x - (float)hv[i]) * LO_SCALE);
  }
  *(f16x4*)&bnh[o] = hv;
  *(f16x4*)&bnl[o] = lv;
}

#define NCAND 10

__launch_bounds__(256)
__global__ void topk_fill(const float* __restrict__ S, _Float16* __restrict__ Phm,
                          _Float16* __restrict__ Plm,
                          const _Float16* __restrict__ bnh, const _Float16* __restrict__ bnl,
                          const int* __restrict__ b2bm, const int* __restrict__ qrw_m,
                          const int* __restrict__ meta, int mmod, int qoff) {
  const int Nb = meta[2 * mmod], nQ = meta[2 * mmod + 1];
  const int q = qoff + blockIdx.x;
  if (q >= nQ) return;
  const int t = threadIdx.x;
  const int wid = t >> 6, ln = t & 63;
  const float4* srow4 = (const float4*)(S + (size_t)blockIdx.x * NB_ROWS);

  // per-thread top-4 over its 32 (approx, pre-masked) sims
  float lv[4] = {-INFINITY, -INFINITY, -INFINITY, -INFINITY};
  int li[4] = {0x7fffffff, 0x7fffffff, 0x7fffffff, 0x7fffffff};
#pragma unroll
  for (int it = 0; it < 8; ++it) {
    const int j = it * 1024 + t * 4;
    float4 f = srow4[j >> 2];
    float e0 = (j + 0 < Nb) ? f.x : -INFINITY;  // guard unwritten tail (poison)
    float e1 = (j + 1 < Nb) ? f.y : -INFINITY;
    float e2 = (j + 2 < Nb) ? f.z : -INFINITY;
    float e3 = (j + 3 < Nb) ? f.w : -INFINITY;
    upd4(e0, j + 0, lv[0], li[0], lv[1], li[1], lv[2], li[2], lv[3], li[3]);
    upd4(e1, j + 1, lv[0], li[0], lv[1], li[1], lv[2], li[2], lv[3], li[3]);
    upd4(e2, j + 2, lv[0], li[0], lv[1], li[1], lv[2], li[2], lv[3], li[3]);
    upd4(e3, j + 3, lv[0], li[0], lv[1], li[1], lv[2], li[2], lv[3], li[3]);
  }

  // iterative global top-NCAND (approx values, exact (desc,idx-asc) order)
  __shared__ float redv[4];
  __shared__ int   redi[4];
  __shared__ float candv[NCAND];
  __shared__ int   candi[NCAND];
  int pos = 0;
  for (int round = 0; round < NCAND; ++round) {
    float mv = (pos < 4) ? lv[pos] : -INFINITY;
    int mi = (pos < 4) ? li[pos] : 0x7fffffff;
    for (int o = 32; o > 0; o >>= 1) {
      float ov = __shfl_down(mv, o, 64);
      int oi = __shfl_down(mi, o, 64);
      if (pair_better(ov, oi, mv, mi)) { mv = ov; mi = oi; }
    }
    if (ln == 0) { redv[wid] = mv; redi[wid] = mi; }
    __syncthreads();
    if (t == 0) {
      float bv = redv[0]; int bi = redi[0];
      for (int wv = 1; wv < 4; ++wv)
        if (pair_better(redv[wv], redi[wv], bv, bi)) { bv = redv[wv]; bi = redi[wv]; }
      candv[round] = bv; candi[round] = bi;
    }
    __syncthreads();
    if (pos < 4 && li[pos] == candi[round]) pos++;
  }

  // exact rescore: dot(bank[qrw[q]], bank[cand]) in fp32 (split-reconstructed)
  const int e = t * 4;
  const size_t qb = (size_t)qrw_m[q] * DDIM + e;
  f16x4 qh = *(const f16x4*)&bnh[qb];
  f16x4 ql = *(const f16x4*)&bnl[qb];
  float qv[4];
#pragma unroll
  for (int i = 0; i < 4; ++i) qv[i] = (float)qh[i] + (float)ql[i] * LO_INV;
  float part[NCAND];
#pragma unroll
  for (int c = 0; c < NCAND; ++c) {
    const int row = (candv[c] == -INFINITY) ? 0 : candi[c];
    const size_t cb = (size_t)row * DDIM + e;
    f16x4 ch = *(const f16x4*)&bnh[cb];
    f16x4 cl = *(const f16x4*)&bnl[cb];
    float s = 0.f;
#pragma unroll
    for (int i = 0; i < 4; ++i)
      s += qv[i] * ((float)ch[i] + (float)cl[i] * LO_INV);
    part[c] = s;
  }
#pragma unroll
  for (int c = 0; c < NCAND; ++c)
    for (int o = 32; o > 0; o >>= 1) part[c] += __shfl_down(part[c], o, 64);
  __shared__ float pr[4][NCAND];
  if (ln == 0)
#pragma unroll
    for (int c = 0; c < NCAND; ++c) pr[wid][c] = part[c];
  __syncthreads();

  __shared__ float wsh[3];
  __shared__ int idsh[3];
  if (t == 0) {
    float a0 = -INFINITY, a1 = -INFINITY, a2 = -INFINITY;
    int j0 = 0x7fffffff, j1 = 0x7fffffff, j2 = 0x7fffffff;
    for (int c = 0; c < NCAND; ++c) {
      float ex = (candv[c] == -INFINITY) ? -INFINITY
                                         : (pr[0][c] + pr[1][c] + pr[2][c] + pr[3][c]);
      upd3(ex, candi[c], a0, j0, a1, j1, a2, j2);
    }
    if (a0 == -INFINITY) {
      wsh[0] = wsh[1] = wsh[2] = 0.f; idsh[0] = idsh[1] = idsh[2] = 0;
    } else {
      const float e1w = (a1 == -INFINITY) ? 0.f : expf(a1 - a0);
      const float e2w = (a2 == -INFINITY) ? 0.f : expf(a2 - a0);
      const float inv = 1.f / (1.f + e1w + e2w);
      wsh[0] = inv; wsh[1] = e1w * inv; wsh[2] = e2w * inv;
      idsh[0] = j0;
      idsh[1] = (a1 == -INFINITY) ? j0 : j1;
      idsh[2] = (a2 == -INFINITY) ? j0 : j2;
    }
  }
  __syncthreads();

  const float w0 = wsh[0], w1 = wsh[1], w2 = wsh[2];
  const size_t r0 = (size_t)b2bm[idsh[0]] * DDIM, r1 = (size_t)b2bm[idsh[1]] * DDIM,
               r2 = (size_t)b2bm[idsh[2]] * DDIM;
  f16x4 h0 = *(const f16x4*)&Phm[r0 + e], l0 = *(const f16x4*)&Plm[r0 + e];
  f16x4 h1v = *(const f16x4*)&Phm[r1 + e], l1 = *(const f16x4*)&Plm[r1 + e];
  f16x4 h2 = *(const f16x4*)&Phm[r2 + e], l2 = *(const f16x4*)&Plm[r2 + e];
  const size_t qoffp = (size_t)qrw_m[q] * DDIM + e;
  f16x4 oh, ol;
#pragma unroll
  for (int i = 0; i < 4; ++i) {
    float a = (float)h0[i] + (float)l0[i] * LO_INV;
    float b = (float)h1v[i] + (float)l1[i] * LO_INV;
    float c = (float)h2[i] + (float)l2[i] * LO_INV;
    float o = w0 * a + w1 * b + w2 * c;
    oh[i] = (_Float16)o;
    ol[i] = (_Float16)((o - (float)oh[i]) * LO_SCALE);
  }
  *(f16x4*)&Phm[qoffp] = oh;
  *(f16x4*)&Plm[qoffp] = ol;
}

__global__ void zero_tail(const int* __restrict__ miss, const int* __restrict__ meta,
                          _Float16* __restrict__ P) {
  const int row = blockIdx.x, m = blockIdx.y;
  if (miss[row] != m + 1) return;
  if (row < meta[2 * m]) return;
  f16x4 z = (f16x4)0;
  const size_t o = (size_t)row * DDIM + threadIdx.x * 4;
  *(f16x4*)&P[(size_t)(2 * m) * PSZ + o] = z;
  *(f16x4*)&P[(size_t)(2 * m + 1) * PSZ + o] = z;
}

__global__ void out_kernel(const _Float16* __restrict__ h1, const float* __restrict__ w2,
                           const float* __restrict__ b2p, float* __restrict__ out) {
  const int row = blockIdx.x, t = threadIdx.x;
  f16x4 h = *(const f16x4*)&h1[(size_t)row * DDIM + t * 4];
  float4 w = *(const float4*)&w2[t * 4];
  float s = (float)h[0] * w.x + (float)h[1] * w.y + (float)h[2] * w.z + (float)h[3] * w.w;
  for (int o = 32; o > 0; o >>= 1) s += __shfl_down(s, o, 64);
  __shared__ float ls[4];
  if ((t & 63) == 0) ls[t >> 6] = s;
  __syncthreads();
  if (t == 0) out[row] = ls[0] + ls[1] + ls[2] + ls[3] + b2p[0];
}

extern "C" void kernel_launch(void* const* d_in, const int* in_sizes, int n_in,
                              void* d_out, int out_size, void* d_ws, size_t ws_size,
                              hipStream_t stream) {
  const float* xs[3] = {(const float*)d_in[0], (const float*)d_in[1], (const float*)d_in[2]};
  const int* miss = (const int*)d_in[3];
  const float* Wm[3] = {(const float*)d_in[4], (const float*)d_in[6], (const float*)d_in[8]};
  const float* bm[3] = {(const float*)d_in[5], (const float*)d_in[7], (const float*)d_in[9]};
  const float* W1 = (const float*)d_in[10];
  const float* b1 = (const float*)d_in[11];
  const float* W2 = (const float*)d_in[12];
  const float* b2v = (const float*)d_in[13];

  char* base = (char*)d_ws;
  size_t off = 0;
  auto carve = [&](size_t bytes) -> void* {
    void* p = base + off;
    off += (bytes + 255) & ~(size_t)255;
    return p;
  };
  int*   meta  = (int*)carve(256);
  int*   b2b   = (int*)carve((size_t)3 * NB_ROWS * sizeof(int));
  int*   qrw   = (int*)carve((size_t)3 * 4096 * sizeof(int));
  _Float16* P = (_Float16*)carve((size_t)6 * PSZ * sizeof(_Float16));  // 96 MB
  char* R1 = (char*)carve((size_t)72 * 1024 * 1024);
  if (off > ws_size) return;  // ~168.1 MB

  const size_t MB = 1024 * 1024;
  // phase 1 aliases:
  _Float16* A2h = (_Float16*)R1;                 // 32 MB
  _Float16* A2l = (_Float16*)(R1 + 32 * MB);     // 32 MB
  _Float16* wth = (_Float16*)(R1 + 64 * MB);     // 4 MB
  _Float16* wtl = (_Float16*)(R1 + 68 * MB);     // 4 MB
  // phase 2 aliases:
  _Float16* bnkh = (_Float16*)R1;                // 16 MB
  _Float16* bnkl = (_Float16*)(R1 + 16 * MB);    // 16 MB
  float*    sim  = (float*)(R1 + 32 * MB);       // 32 MB
  // phase 3 aliases:
  _Float16* W1t   = (_Float16*)R1;               // 6 MB
  _Float16* h1f16 = (_Float16*)(R1 + 32 * MB);   // 16 MB

  scan_kernel<<<dim3(3), dim3(256), 0, stream>>>(miss, meta, b2b, qrw);

  for (int m = 0; m < 3; ++m) {
    tsplit<<<dim3(64, 32), dim3(32, 8), 0, stream>>>(Wm[m], wth, wtl, 2048, 1024);
    xsplit<<<dim3(8192), dim3(256), 0, stream>>>(xs[m], A2h, A2l);
    gemm_proj_mfma<<<dim3(8, 64), dim3(256), 0, stream>>>(
        A2h, A2l, wth, wtl, bm[m], P + (size_t)(2 * m) * PSZ, P + (size_t)(2 * m + 1) * PSZ);
  }

  for (int m = 0; m < 3; ++m) {
    build_bnk<<<dim3(NB_ROWS), dim3(256), 0, stream>>>(
        P + (size_t)(2 * m) * PSZ, P + (size_t)(2 * m + 1) * PSZ,
        b2b + m * NB_ROWS, meta, m, bnkh, bnkl);
    for (int c = 0; c < 4; ++c) {
      gemm_sim_mfma<<<dim3(64, 8), dim3(256), 0, stream>>>(
          bnkh, qrw + m * 4096, meta, miss, m, c * 1024, sim);
      topk_fill<<<dim3(1024), dim3(256), 0, stream>>>(
          sim, P + (size_t)(2 * m) * PSZ, P + (size_t)(2 * m + 1) * PSZ,
          bnkh, bnkl, b2b + m * NB_ROWS, qrw + m * 4096, meta, m, c * 1024);
    }
  }

  zero_tail<<<dim3(NB_ROWS, 3), dim3(256), 0, stream>>>(miss, meta, P);
  tsplit<<<dim3(96, 32), dim3(32, 8), 0, stream>>>(W1, W1t, (_Float16*)nullptr, 3072, 1024);
  gemm_h1_mfma<<<dim3(8, 64), dim3(256), 0, stream>>>(P, W1t, b1, h1f16);
  out_kernel<<<dim3(NB_ROWS), dim3(256), 0, stream>>>(h1f16, W2, b2v, (float*)d_out);
}